// Round 7
// baseline (105.460 us; speedup 1.0000x reference)
//
#include <hip/hip_runtime.h>
#include <stdint.h>

// CausalMemory: out = ((q @ k^T) .* decay_mask) @ v @ Wo * scale
// B=4, T=2048, V=1024, D=512.  bf16 MFMA 16x16x32, fp32 accum.
// Round 7: depth-3 prefetch pipeline, counted vmcnt(3), ONE barrier/step
// (loads for tile t+1 stay in flight across the barrier -> no full drain).
// Skinny tiles for grid fill: QKV/out 128x64 (1536/1024 blocks), S/R 64x128.

using bf16u = unsigned short;
using short8 = __attribute__((ext_vector_type(8))) short;
using f32x4  = __attribute__((ext_vector_type(4))) float;

__device__ __forceinline__ unsigned short f2bf(float f) {
  unsigned int u = __float_as_uint(f);
  u += 0x7fffu + ((u >> 16) & 1u);   // round-to-nearest-even
  return (unsigned short)(u >> 16);
}

__device__ __forceinline__ void gload16(const void* g, void* l) {
  __builtin_amdgcn_global_load_lds(
      (const __attribute__((address_space(1))) void*)g,
      (__attribute__((address_space(3))) void*)l, 16, 0, 0);
}

template<int N> __device__ __forceinline__ void waitvm() {
  if constexpr (N == 0)      asm volatile("s_waitcnt vmcnt(0)" ::: "memory");
  else if constexpr (N == 3) asm volatile("s_waitcnt vmcnt(3)" ::: "memory");
  else                       asm volatile("s_waitcnt vmcnt(4)" ::: "memory");
}

#define BK 32

// C = A @ Bt^T with row strides.  A: [M][ldA] bf16, Bt: [N][ldB] bf16.
// MODE 0: bf16 store.
// MODE 1: banded S: nbx=2 (delta); rb128 = 128-row block of bm; B rows start
//         at (rb128+delta)*128; decay mask (0 for diff<=0 or col>=2048);
//         store S_band[z][row][delta*128+c]  (ldC = 256).
// MODE 2: f32 * scale store (final out).
// MODE 3: R-band: A = S_band rows, B k-coords offset by bm&~127.
template<int MODE, int TBM, int TBN>
__global__ __launch_bounds__(256, 4)
void gemm_bt(const bf16u* __restrict__ A, const bf16u* __restrict__ Bt,
             void* __restrict__ Cout,
             int K, int ldA, int ldB, int ldC,
             long sA, long sB, long sC,
             int nbx, const float* __restrict__ scal)
{
  constexpr int WR = TBM / 2, WC = TBN / 2;       // per-wave tile (2x2 waves)
  constexpr int MF = WR / 16, NF = WC / 16;       // fragment counts
  constexpr int RA = TBM / 64, RB = TBN / 64;     // staging rounds
  constexpr int L  = RA + RB;                     // gloads per thread per tile

  __shared__ bf16u Al[3][TBM * BK];
  __shared__ bf16u Bl[3][TBN * BK];
  const int z = blockIdx.z;
  A  += (long)z * sA;
  Bt += (long)z * sB;

  // bijective XCD swizzle (m204) + row-major decode
  const int nwg  = gridDim.x;
  const int orig = blockIdx.x;
  const int q8 = nwg >> 3, r8 = nwg & 7;
  const int xcd = orig & 7, lid = orig >> 3;
  const int wgid = (xcd < r8 ? xcd * (q8 + 1)
                             : r8 * (q8 + 1) + (xcd - r8) * q8) + lid;
  const int by = wgid / nbx, bx = wgid - by * nbx;
  const int bm = by * TBM;
  const int rb128 = bm >> 7;
  const int bn = (MODE == 1) ? (rb128 + bx) * TBN : bx * TBN;
  const int kofsB = (MODE == 3) ? (bm & ~127) : 0;

  const int tid  = threadIdx.x;
  const int wid  = tid >> 6;
  const int lane = tid & 63;
  const int wr = (wid >> 1) * WR;
  const int wc = (wid & 1) * WC;

  f32x4 acc[MF][NF] = {};

  // Staging: linear LDS dest (wave-uniform base + lane*16), pre-swizzled
  // global source.  LDS (row, chunk c) holds global chunk c ^ ((row>>1)&3).
  // Each 4096-B round covers 64 rows (64 B/row); +64 rows keeps (row>>1)&3.
  const int base0 = wid * 1024;
  const int lin0  = base0 + lane * 16;
  const int r0row = lin0 >> 6;            // 0..63 within round
  const int c16   = (lin0 >> 4) & 3;
  const int rcol  = (c16 ^ ((r0row >> 1) & 3)) << 3;

  const int nt = K / BK;

  auto stage = [&](int buf, int kk) {
#pragma unroll
    for (int r = 0; r < RA; ++r)
      gload16(A + (long)(bm + r * 64 + r0row) * ldA + kk + rcol,
              (char*)&Al[buf][0] + r * 4096 + base0);
#pragma unroll
    for (int r = 0; r < RB; ++r)
      gload16(Bt + (long)(bn + r * 64 + r0row) * ldB + kofsB + kk + rcol,
              (char*)&Bl[buf][0] + r * 4096 + base0);
  };

  // prologue: tiles 0 and 1 in flight
  stage(0, 0);
  if (nt > 1) stage(1, BK);

  const int fr = lane & 15;
  const int kc = lane >> 4;
  int cur = 0;
  for (int t = 0; t < nt; ++t) {
    // wait for tile t's loads (allow t+1's L loads to stay in flight)
    if (t + 1 < nt) waitvm<L>(); else waitvm<0>();
    __builtin_amdgcn_s_barrier();          // all waves' tile-t loads landed
    __builtin_amdgcn_sched_barrier(0);
    // issue tile t+2 into buf (t+2)%3 == (t-1)%3: its last readers finished
    // before this barrier (their lgkm-gated MFMAs were in iter t-1).
    if (t + 2 < nt) {
      int nx = cur + 2; if (nx >= 3) nx -= 3;
      stage(nx, (t + 2) * BK);
    }
    short8 af[MF], bfr[NF];
#pragma unroll
    for (int m = 0; m < MF; ++m) {
      int row = wr + m * 16 + fr;
      af[m] = *(const short8*)&Al[cur][row * BK + ((kc ^ ((row >> 1) & 3)) << 3)];
    }
#pragma unroll
    for (int n = 0; n < NF; ++n) {
      int row = wc + n * 16 + fr;
      bfr[n] = *(const short8*)&Bl[cur][row * BK + ((kc ^ ((row >> 1) & 3)) << 3)];
    }
#pragma unroll
    for (int m = 0; m < MF; ++m)
#pragma unroll
      for (int n = 0; n < NF; ++n)
        acc[m][n] = __builtin_amdgcn_mfma_f32_16x16x32_bf16(af[m], bfr[n], acc[m][n], 0, 0, 0);
    ++cur; if (cur == 3) cur = 0;
  }

  // Epilogue.  C/D layout: col = lane&15, row = (lane>>4)*4 + j  (m89/m91)
  const int cc = lane & 15;
  const int cr = (lane >> 4) * 4;
  float mul = 1.0f, l2d = 0.0f;
  if (MODE == 1) {
    float dlv = scal[0];
    float decay = 1.0f / (1.0f + __expf(-dlv));   // sigmoid
    l2d = __log2f(decay);
  } else if (MODE == 2) {
    mul = scal[0];
  }

#pragma unroll
  for (int m = 0; m < MF; ++m) {
#pragma unroll
    for (int n = 0; n < NF; ++n) {
#pragma unroll
      for (int j = 0; j < 4; ++j) {
        int row = bm + wr + m * 16 + cr + j;
        int col = bn + wc + n * 16 + cc;
        float val = acc[m][n][j];
        if (MODE == 1) {
          int diff = col - row;
          float w = (diff > 0 && col < 2048)
                        ? exp2f((float)(diff - 1) * l2d) : 0.0f;
          int lc = bx * 128 + (wc + n * 16 + cc);   // band-local column
          ((bf16u*)Cout)[(long)z * sC + (long)row * ldC + lc] = f2bf(val * w);
        } else if (MODE == 2) {
          ((float*)Cout)[(long)z * sC + (long)row * ldC + col] = val * mul;
        } else {
          ((bf16u*)Cout)[(long)z * sC + (long)row * ldC + col] = f2bf(val);
        }
      }
    }
  }
}

// f32 -> bf16 elementwise, 4 at a time
__global__ void cvt4(const float4* __restrict__ in, ushort4* __restrict__ out, int n4) {
  int i = blockIdx.x * 256 + threadIdx.x;
  if (i < n4) {
    float4 v = in[i];
    ushort4 o;
    o.x = f2bf(v.x); o.y = f2bf(v.y); o.z = f2bf(v.z); o.w = f2bf(v.w);
    out[i] = o;
  }
}

// merged transpose+convert for all 4 weights: z picks which.
__global__ void tconvAll(const float* __restrict__ Wq, const float* __restrict__ Wk,
                         const float* __restrict__ Wv, const float* __restrict__ Wo,
                         bf16u* __restrict__ WqT, bf16u* __restrict__ WkT,
                         bf16u* __restrict__ WvT, bf16u* __restrict__ WoT,
                         int V, int D) {
  __shared__ float t[32][33];
  const int zz = blockIdx.z;
  const float* in; bf16u* out; int R, C;
  if (zz == 0)      { in = Wq; out = WqT; R = V; C = D; }
  else if (zz == 1) { in = Wk; out = WkT; R = V; C = D; }
  else if (zz == 2) { in = Wv; out = WvT; R = V; C = D; }
  else              { in = Wo; out = WoT; R = D; C = V; }
  int c0 = blockIdx.x * 32, r0 = blockIdx.y * 32;
  if (c0 >= C || r0 >= R) return;
  int tx = threadIdx.x, ty = threadIdx.y;   // 32x8
#pragma unroll
  for (int i = 0; i < 4; ++i)
    t[ty + 8 * i][tx] = in[(long)(r0 + ty + 8 * i) * C + c0 + tx];
  __syncthreads();
#pragma unroll
  for (int i = 0; i < 4; ++i)
    out[(long)(c0 + ty + 8 * i) * R + r0 + tx] = f2bf(t[tx][ty + 8 * i]);
}

// batched strided bf16 transpose: in [R x C, row-stride ldIn] -> out [C][R]
__global__ void tr16(const bf16u* __restrict__ in, bf16u* __restrict__ out,
                     int R, int C, int ldIn, long sIn, long sOut) {
  __shared__ bf16u t[32][33];
  in  += (long)blockIdx.z * sIn;
  out += (long)blockIdx.z * sOut;
  int c0 = blockIdx.x * 32, r0 = blockIdx.y * 32;
  int tx = threadIdx.x, ty = threadIdx.y;
#pragma unroll
  for (int i = 0; i < 4; ++i)
    t[ty + 8 * i][tx] = in[(long)(r0 + ty + 8 * i) * ldIn + c0 + tx];
  __syncthreads();
#pragma unroll
  for (int i = 0; i < 4; ++i)
    out[(long)(c0 + ty + 8 * i) * R + r0 + tx] = t[tx][ty + 8 * i];
}

extern "C" void kernel_launch(void* const* d_in, const int* in_sizes, int n_in,
                              void* d_out, int out_size, void* d_ws, size_t ws_size,
                              hipStream_t stream) {
  const float* x  = (const float*)d_in[0];
  const float* dl = (const float*)d_in[1];
  const float* sc = (const float*)d_in[2];
  const float* Wq = (const float*)d_in[3];
  const float* Wk = (const float*)d_in[4];
  const float* Wv = (const float*)d_in[5];
  const float* Wo = (const float*)d_in[6];

  const int B = 4, T = 2048, V = 1024, D = 512;
  const long MT = (long)B * T;   // 8192
  const int QKV = 3 * D;         // 1536
  const int BAND = 256;          // 2 x 128 band columns (delta 0..1)

  char* p = (char*)d_ws;
  auto alloc = [&](size_t bytes) { char* r = p; p += bytes; return r; };
  bf16u* x16 = (bf16u*)alloc((size_t)MT * V * 2);        // 16 MB
  bf16u* WqT = (bf16u*)alloc((size_t)D * V * 2);         // contiguous [1536][V]
  bf16u* WkT = (bf16u*)alloc((size_t)D * V * 2);
  bf16u* WvT = (bf16u*)alloc((size_t)D * V * 2);
  bf16u* WoT = (bf16u*)alloc((size_t)V * D * 2);
  bf16u* qkv = (bf16u*)alloc((size_t)MT * QKV * 2);      // 25 MB
  bf16u* vT  = (bf16u*)alloc((size_t)MT * D * 2 + 4096); // 8 MB + guard
  bf16u* Sb  = (bf16u*)alloc((size_t)B * T * BAND * 2);  // 4.2 MB band
  bf16u* R   = (bf16u*)alloc((size_t)MT * D * 2);        // 8 MB

  // 1. convert x to bf16
  int n4 = (int)(MT * V / 4);
  cvt4<<<(n4 + 255) / 256, 256, 0, stream>>>((const float4*)x, (ushort4*)x16, n4);

  // 2. weight transposes (single launch)
  tconvAll<<<dim3(32, 32, 4), dim3(32, 8), 0, stream>>>(
      Wq, Wk, Wv, Wo, WqT, WkT, WvT, WoT, V, D);

  // 3. qkv = x16 @ [Wq|Wk|Wv]^T  (M=8192, N=1536, K=1024), 128x64 -> 1536 blocks
  gemm_bt<0, 128, 64><<<dim3(64 * 24, 1, 1), 256, 0, stream>>>(
      x16, WqT, qkv, V, V, V, QKV, 0, 0, 0, 24, nullptr);

  // 4. v transpose per batch: [T][D] (stride 1536) -> [D][T]
  tr16<<<dim3(D / 32, T / 32, B), dim3(32, 8), 0, stream>>>(
      qkv + 2 * D, vT, T, D, QKV, (long)T * QKV, (long)D * T);

  // 5. banded scores, 64x128 tiles: S_band[b][t][delta*128+c]
  gemm_bt<1, 64, 128><<<dim3(32 * 2, 1, B), 256, 0, stream>>>(
      qkv, qkv + D, Sb, D, QKV, QKV, BAND,
      (long)T * QKV, (long)T * QKV, (long)T * BAND, 2, dl);

  // 6. banded retrieved, 64x128: R rows [bm,+64) = S_band @ v[s = (bm&~127)..+256)
  gemm_bt<3, 64, 128><<<dim3(32 * 4, 1, B), 256, 0, stream>>>(
      Sb, vT, R, BAND, BAND, T, D,
      (long)T * BAND, (long)1 << 20, (long)T * D, 4, nullptr);

  // 7. out = R @ Wo^T * scale  (M=8192, N=1024, K=512), 128x64 -> 1024 blocks
  gemm_bt<2, 128, 64><<<dim3(64 * 16, 1, 1), 256, 0, stream>>>(
      R, WoT, d_out, D, D, D, V, 0, 0, 0, 16, sc);
}

// Round 8
// 96.463 us; speedup vs baseline: 1.0933x; 1.0933x over previous
//
#include <hip/hip_runtime.h>
#include <stdint.h>

// CausalMemory: out = ((q @ k^T) .* decay_mask) @ v @ Wo * scale
// B=4, T=2048, V=1024, D=512.  bf16 MFMA 16x16x32, fp32 accum.
// Round 8: depth-3 counted-vmcnt pipeline at the PROVEN 128^2 geometry
// (round 7 confounded the pipeline with skinny tiles; this isolates it).
// vmcnt(4) retires exactly tile t; tile t+1's loads stay in flight across
// the barrier -> no full vmcnt(0) drain per K-step.

using bf16u = unsigned short;
using short8 = __attribute__((ext_vector_type(8))) short;
using f32x4  = __attribute__((ext_vector_type(4))) float;

__device__ __forceinline__ unsigned short f2bf(float f) {
  unsigned int u = __float_as_uint(f);
  u += 0x7fffu + ((u >> 16) & 1u);   // round-to-nearest-even
  return (unsigned short)(u >> 16);
}

__device__ __forceinline__ void gload16(const void* g, void* l) {
  __builtin_amdgcn_global_load_lds(
      (const __attribute__((address_space(1))) void*)g,
      (__attribute__((address_space(3))) void*)l, 16, 0, 0);
}

template<int N> __device__ __forceinline__ void waitvm() {
  if constexpr (N == 0)      asm volatile("s_waitcnt vmcnt(0)" ::: "memory");
  else if constexpr (N == 2) asm volatile("s_waitcnt vmcnt(2)" ::: "memory");
  else if constexpr (N == 3) asm volatile("s_waitcnt vmcnt(3)" ::: "memory");
  else if constexpr (N == 4) asm volatile("s_waitcnt vmcnt(4)" ::: "memory");
  else if constexpr (N == 6) asm volatile("s_waitcnt vmcnt(6)" ::: "memory");
}

#define BK 32

// C = A @ Bt^T with row strides.  A: [M][ldA] bf16, Bt: [N][ldB] bf16.
// MODE 0: bf16 store.
// MODE 1: banded S: nbx=2 (delta); rb128 = bm>>7; B rows start at
//         (rb128+delta)*128; decay mask (0 for diff<=0 or col>=2048);
//         store S_band[z][row][delta*128+c]  (ldC = 256).
// MODE 2: f32 * scale store (final out).
// MODE 3: R-band: A = S_band rows, B k-coords offset by bm&~127.
template<int MODE, int TBM, int TBN>
__global__ __launch_bounds__(256, 4)
void gemm_bt(const bf16u* __restrict__ A, const bf16u* __restrict__ Bt,
             void* __restrict__ Cout,
             int K, int ldA, int ldB, int ldC,
             long sA, long sB, long sC,
             int nbx, const float* __restrict__ scal)
{
  constexpr int WR = TBM / 2, WC = TBN / 2;       // per-wave tile (2x2 waves)
  constexpr int MF = WR / 16, NF = WC / 16;       // fragment counts
  constexpr int RA = TBM / 64, RB = TBN / 64;     // staging rounds
  constexpr int L  = RA + RB;                     // gloads/thread per tile

  __shared__ bf16u Al[3][TBM * BK];   // 3 x 8 KB
  __shared__ bf16u Bl[3][TBN * BK];   // 3 x 8 KB  (48 KB total)
  const int z = blockIdx.z;
  A  += (long)z * sA;
  Bt += (long)z * sB;

  // bijective XCD swizzle (m204) + row-major decode
  const int nwg  = gridDim.x;
  const int orig = blockIdx.x;
  const int q8 = nwg >> 3, r8 = nwg & 7;
  const int xcd = orig & 7, lid = orig >> 3;
  const int wgid = (xcd < r8 ? xcd * (q8 + 1)
                             : r8 * (q8 + 1) + (xcd - r8) * q8) + lid;
  const int by = wgid / nbx, bx = wgid - by * nbx;
  const int bm = by * TBM;
  const int rb128 = bm >> 7;
  const int bn = (MODE == 1) ? (rb128 + bx) * TBN : bx * TBN;
  const int kofsB = (MODE == 3) ? (bm & ~127) : 0;

  const int tid  = threadIdx.x;
  const int wid  = tid >> 6;
  const int lane = tid & 63;
  const int wr = (wid >> 1) * WR;
  const int wc = (wid & 1) * WC;

  f32x4 acc[MF][NF] = {};

  // Staging: linear LDS dest (wave-uniform base + lane*16), pre-swizzled
  // global source.  LDS (row, chunk c) holds global chunk c ^ ((row>>1)&3).
  const int base0 = wid * 1024;
  const int lin0  = base0 + lane * 16;
  const int r0row = lin0 >> 6;            // 0..63 within a 4096-B round
  const int c16   = (lin0 >> 4) & 3;
  const int rcol  = (c16 ^ ((r0row >> 1) & 3)) << 3;

  const int nt = K / BK;

  auto stage = [&](int buf, int kk) {
#pragma unroll
    for (int r = 0; r < RA; ++r)
      gload16(A + (long)(bm + r * 64 + r0row) * ldA + kk + rcol,
              (char*)&Al[buf][0] + r * 4096 + base0);
#pragma unroll
    for (int r = 0; r < RB; ++r)
      gload16(Bt + (long)(bn + r * 64 + r0row) * ldB + kofsB + kk + rcol,
              (char*)&Bl[buf][0] + r * 4096 + base0);
  };

  // prologue: tiles 0 and 1 in flight
  stage(0, 0);
  if (nt > 1) stage(1, BK);

  const int fr = lane & 15;
  const int kc = lane >> 4;
  int cur = 0;
  for (int t = 0; t < nt; ++t) {
    // retire exactly tile t's L loads; tile t+1's stay in flight
    if (t + 1 < nt) waitvm<L>(); else waitvm<0>();
    __builtin_amdgcn_s_barrier();          // all waves' tile-t loads landed
    __builtin_amdgcn_sched_barrier(0);
    // issue tile t+2 into buf (t+2)%3 == (t-1)%3: every wave's t-1 ds_reads
    // completed (lgkm-gated MFMA) before it reached this barrier.
    if (t + 2 < nt) {
      int nx = cur + 2; if (nx >= 3) nx -= 3;
      stage(nx, (t + 2) * BK);
    }
    short8 af[MF], bfr[NF];
#pragma unroll
    for (int m = 0; m < MF; ++m) {
      int row = wr + m * 16 + fr;
      af[m] = *(const short8*)&Al[cur][row * BK + ((kc ^ ((row >> 1) & 3)) << 3)];
    }
#pragma unroll
    for (int n = 0; n < NF; ++n) {
      int row = wc + n * 16 + fr;
      bfr[n] = *(const short8*)&Bl[cur][row * BK + ((kc ^ ((row >> 1) & 3)) << 3)];
    }
#pragma unroll
    for (int m = 0; m < MF; ++m)
#pragma unroll
      for (int n = 0; n < NF; ++n)
        acc[m][n] = __builtin_amdgcn_mfma_f32_16x16x32_bf16(af[m], bfr[n], acc[m][n], 0, 0, 0);
    ++cur; if (cur == 3) cur = 0;
  }

  // Epilogue.  C/D layout: col = lane&15, row = (lane>>4)*4 + j  (m89/m91)
  const int cc = lane & 15;
  const int cr = (lane >> 4) * 4;
  float mul = 1.0f, l2d = 0.0f;
  if (MODE == 1) {
    float dlv = scal[0];
    float decay = 1.0f / (1.0f + __expf(-dlv));   // sigmoid
    l2d = __log2f(decay);
  } else if (MODE == 2) {
    mul = scal[0];
  }

#pragma unroll
  for (int m = 0; m < MF; ++m) {
#pragma unroll
    for (int n = 0; n < NF; ++n) {
#pragma unroll
      for (int j = 0; j < 4; ++j) {
        int row = bm + wr + m * 16 + cr + j;
        int col = bn + wc + n * 16 + cc;
        float val = acc[m][n][j];
        if (MODE == 1) {
          int diff = col - row;
          float w = (diff > 0 && col < 2048)
                        ? exp2f((float)(diff - 1) * l2d) : 0.0f;
          int lc = bx * 128 + (wc + n * 16 + cc);   // band-local column
          ((bf16u*)Cout)[(long)z * sC + (long)row * ldC + lc] = f2bf(val * w);
        } else if (MODE == 2) {
          ((float*)Cout)[(long)z * sC + (long)row * ldC + col] = val * mul;
        } else {
          ((bf16u*)Cout)[(long)z * sC + (long)row * ldC + col] = f2bf(val);
        }
      }
    }
  }
}

// f32 -> bf16 elementwise, 4 at a time
__global__ void cvt4(const float4* __restrict__ in, ushort4* __restrict__ out, int n4) {
  int i = blockIdx.x * 256 + threadIdx.x;
  if (i < n4) {
    float4 v = in[i];
    ushort4 o;
    o.x = f2bf(v.x); o.y = f2bf(v.y); o.z = f2bf(v.z); o.w = f2bf(v.w);
    out[i] = o;
  }
}

// merged transpose+convert for all 4 weights: z picks which.
__global__ void tconvAll(const float* __restrict__ Wq, const float* __restrict__ Wk,
                         const float* __restrict__ Wv, const float* __restrict__ Wo,
                         bf16u* __restrict__ WqT, bf16u* __restrict__ WkT,
                         bf16u* __restrict__ WvT, bf16u* __restrict__ WoT,
                         int V, int D) {
  __shared__ float t[32][33];
  const int zz = blockIdx.z;
  const float* in; bf16u* out; int R, C;
  if (zz == 0)      { in = Wq; out = WqT; R = V; C = D; }
  else if (zz == 1) { in = Wk; out = WkT; R = V; C = D; }
  else if (zz == 2) { in = Wv; out = WvT; R = V; C = D; }
  else              { in = Wo; out = WoT; R = D; C = V; }
  int c0 = blockIdx.x * 32, r0 = blockIdx.y * 32;
  if (c0 >= C || r0 >= R) return;
  int tx = threadIdx.x, ty = threadIdx.y;   // 32x8
#pragma unroll
  for (int i = 0; i < 4; ++i)
    t[ty + 8 * i][tx] = in[(long)(r0 + ty + 8 * i) * C + c0 + tx];
  __syncthreads();
#pragma unroll
  for (int i = 0; i < 4; ++i)
    out[(long)(c0 + ty + 8 * i) * R + r0 + tx] = f2bf(t[tx][ty + 8 * i]);
}

// batched strided bf16 transpose: in [R x C, row-stride ldIn] -> out [C][R]
__global__ void tr16(const bf16u* __restrict__ in, bf16u* __restrict__ out,
                     int R, int C, int ldIn, long sIn, long sOut) {
  __shared__ bf16u t[32][33];
  in  += (long)blockIdx.z * sIn;
  out += (long)blockIdx.z * sOut;
  int c0 = blockIdx.x * 32, r0 = blockIdx.y * 32;
  int tx = threadIdx.x, ty = threadIdx.y;
#pragma unroll
  for (int i = 0; i < 4; ++i)
    t[ty + 8 * i][tx] = in[(long)(r0 + ty + 8 * i) * ldIn + c0 + tx];
  __syncthreads();
#pragma unroll
  for (int i = 0; i < 4; ++i)
    out[(long)(c0 + ty + 8 * i) * R + r0 + tx] = t[tx][ty + 8 * i];
}

extern "C" void kernel_launch(void* const* d_in, const int* in_sizes, int n_in,
                              void* d_out, int out_size, void* d_ws, size_t ws_size,
                              hipStream_t stream) {
  const float* x  = (const float*)d_in[0];
  const float* dl = (const float*)d_in[1];
  const float* sc = (const float*)d_in[2];
  const float* Wq = (const float*)d_in[3];
  const float* Wk = (const float*)d_in[4];
  const float* Wv = (const float*)d_in[5];
  const float* Wo = (const float*)d_in[6];

  const int B = 4, T = 2048, V = 1024, D = 512;
  const long MT = (long)B * T;   // 8192
  const int QKV = 3 * D;         // 1536
  const int BAND = 256;          // 2 x 128 band columns (delta 0..1)

  char* p = (char*)d_ws;
  auto alloc = [&](size_t bytes) { char* r = p; p += bytes; return r; };
  bf16u* x16 = (bf16u*)alloc((size_t)MT * V * 2);        // 16 MB
  bf16u* WqT = (bf16u*)alloc((size_t)D * V * 2);         // contiguous [1536][V]
  bf16u* WkT = (bf16u*)alloc((size_t)D * V * 2);
  bf16u* WvT = (bf16u*)alloc((size_t)D * V * 2);
  bf16u* WoT = (bf16u*)alloc((size_t)V * D * 2);
  bf16u* qkv = (bf16u*)alloc((size_t)MT * QKV * 2);      // 25 MB
  bf16u* vT  = (bf16u*)alloc((size_t)MT * D * 2 + 4096); // 8 MB + guard
  bf16u* Sb  = (bf16u*)alloc((size_t)B * T * BAND * 2);  // 4.2 MB band
  bf16u* R   = (bf16u*)alloc((size_t)MT * D * 2);        // 8 MB

  // 1. convert x to bf16
  int n4 = (int)(MT * V / 4);
  cvt4<<<(n4 + 255) / 256, 256, 0, stream>>>((const float4*)x, (ushort4*)x16, n4);

  // 2. weight transposes (single launch)
  tconvAll<<<dim3(32, 32, 4), dim3(32, 8), 0, stream>>>(
      Wq, Wk, Wv, Wo, WqT, WkT, WvT, WoT, V, D);

  // 3. qkv = x16 @ [Wq|Wk|Wv]^T  (M=8192, N=1536, K=1024), 128^2 -> 768 blocks
  gemm_bt<0, 128, 128><<<dim3(64 * 12, 1, 1), 256, 0, stream>>>(
      x16, WqT, qkv, V, V, V, QKV, 0, 0, 0, 12, nullptr);

  // 4. v transpose per batch: [T][D] (stride 1536) -> [D][T]
  tr16<<<dim3(D / 32, T / 32, B), dim3(32, 8), 0, stream>>>(
      qkv + 2 * D, vT, T, D, QKV, (long)T * QKV, (long)D * T);

  // 5. banded scores: S_band[b][t][delta*128+c], 128^2 tiles
  gemm_bt<1, 128, 128><<<dim3(16 * 2, 1, B), 256, 0, stream>>>(
      qkv, qkv + D, Sb, D, QKV, QKV, BAND,
      (long)T * QKV, (long)T * QKV, (long)T * BAND, 2, dl);

  // 6. banded retrieved: R rows [bm,+128) = S_band @ v[s = bm..bm+256)
  gemm_bt<3, 128, 128><<<dim3(16 * 4, 1, B), 256, 0, stream>>>(
      Sb, vT, R, BAND, BAND, T, D,
      (long)T * BAND, (long)1 << 20, (long)T * D, 4, nullptr);

  // 7. out = R @ Wo^T * scale  (M=8192, N=1024, K=512), 128^2 -> 512 blocks
  gemm_bt<2, 128, 128><<<dim3(64 * 8, 1, 1), 256, 0, stream>>>(
      R, WoT, d_out, D, D, D, V, 0, 0, 0, 8, sc);
}

// Round 9
// 95.924 us; speedup vs baseline: 1.0994x; 1.0056x over previous
//
#include <hip/hip_runtime.h>
#include <stdint.h>

// CausalMemory: out = ((q @ k^T) .* decay_mask) @ v @ Wo * scale
// B=4, T=2048, V=1024, D=512.  bf16 MFMA, fp32 accum.
// Round 9: 32x32x16 MFMA (µbench +15% vs 16x16x32; halves MFMA issue slots);
// cvt4+tconvAll merged into one prep dispatch.  Banded S/R kept (delta 0..1).
// C/D layout (m74/m101): col=lane&31, row=(r&3)+8*(r>>2)+4*(lane>>5).

using bf16u = unsigned short;
using short8 = __attribute__((ext_vector_type(8))) short;
using f32x16 = __attribute__((ext_vector_type(16))) float;

__device__ __forceinline__ unsigned short f2bf(float f) {
  unsigned int u = __float_as_uint(f);
  u += 0x7fffu + ((u >> 16) & 1u);   // round-to-nearest-even
  return (unsigned short)(u >> 16);
}

__device__ __forceinline__ void gload16(const void* g, void* l) {
  __builtin_amdgcn_global_load_lds(
      (const __attribute__((address_space(1))) void*)g,
      (__attribute__((address_space(3))) void*)l, 16, 0, 0);
}

template<int N> __device__ __forceinline__ void waitvm() {
  if constexpr (N == 0)      asm volatile("s_waitcnt vmcnt(0)" ::: "memory");
  else if constexpr (N == 4) asm volatile("s_waitcnt vmcnt(4)" ::: "memory");
}

#define BK 32

// C = A @ Bt^T with row strides.  A: [M][ldA] bf16, Bt: [N][ldB] bf16.
// MODE 0: bf16 store.
// MODE 1: banded S: nbx=2 (delta); B rows start at (bm>>7 + delta)*128;
//         decay mask (0 for diff<=0 or col>=2048); store ldC=256 band.
// MODE 2: f32 * scale store (final out).
// MODE 3: R-band: A = S_band rows, B k-coords offset by bm.
template<int MODE, int TBM, int TBN>
__global__ __launch_bounds__(256, 4)
void gemm_bt(const bf16u* __restrict__ A, const bf16u* __restrict__ Bt,
             void* __restrict__ Cout,
             int K, int ldA, int ldB, int ldC,
             long sA, long sB, long sC,
             int nbx, const float* __restrict__ scal)
{
  constexpr int WR = TBM / 2, WC = TBN / 2;       // per-wave tile (2x2 waves)
  constexpr int MF = WR / 32, NF = WC / 32;       // 32x32 fragment counts
  constexpr int RA = TBM / 64, RB = TBN / 64;     // staging rounds
  constexpr int L  = RA + RB;                     // gloads/thread per tile

  __shared__ bf16u Al[3][TBM * BK];   // 3 x 8 KB
  __shared__ bf16u Bl[3][TBN * BK];   // 3 x 8 KB
  const int z = blockIdx.z;
  A  += (long)z * sA;
  Bt += (long)z * sB;

  // bijective XCD swizzle (m204) + row-major decode
  const int nwg  = gridDim.x;
  const int orig = blockIdx.x;
  const int q8 = nwg >> 3, r8 = nwg & 7;
  const int xcd = orig & 7, lid = orig >> 3;
  const int wgid = (xcd < r8 ? xcd * (q8 + 1)
                             : r8 * (q8 + 1) + (xcd - r8) * q8) + lid;
  const int by = wgid / nbx, bx = wgid - by * nbx;
  const int bm = by * TBM;
  const int bn = (MODE == 1) ? ((bm >> 7) + bx) * TBN : bx * TBN;
  const int kofsB = (MODE == 3) ? (bm & ~127) : 0;

  const int tid  = threadIdx.x;
  const int wid  = tid >> 6;
  const int lane = tid & 63;
  const int wr = (wid >> 1) * WR;
  const int wc = (wid & 1) * WC;

  f32x16 acc[MF][NF] = {};

  // Staging: linear LDS dest (wave-uniform base + lane*16), pre-swizzled
  // global source.  LDS (row, chunk c) holds global chunk c ^ ((row>>1)&3).
  const int base0 = wid * 1024;
  const int lin0  = base0 + lane * 16;
  const int r0row = lin0 >> 6;            // 0..63 within a 4096-B round
  const int c16   = (lin0 >> 4) & 3;
  const int rcol  = (c16 ^ ((r0row >> 1) & 3)) << 3;

  const int nt = K / BK;

  auto stage = [&](int buf, int kk) {
#pragma unroll
    for (int r = 0; r < RA; ++r)
      gload16(A + (long)(bm + r * 64 + r0row) * ldA + kk + rcol,
              (char*)&Al[buf][0] + r * 4096 + base0);
#pragma unroll
    for (int r = 0; r < RB; ++r)
      gload16(Bt + (long)(bn + r * 64 + r0row) * ldB + kofsB + kk + rcol,
              (char*)&Bl[buf][0] + r * 4096 + base0);
  };

  // prologue: tiles 0 and 1 in flight
  stage(0, 0);
  if (nt > 1) stage(1, BK);

  const int r31 = lane & 31;
  const int hi  = lane >> 5;     // k-half within fragment
  int cur = 0;
  for (int t = 0; t < nt; ++t) {
    if (t + 1 < nt) waitvm<L>(); else waitvm<0>();
    __builtin_amdgcn_s_barrier();
    __builtin_amdgcn_sched_barrier(0);
    if (t + 2 < nt) {
      int nx = cur + 2; if (nx >= 3) nx -= 3;
      stage(nx, (t + 2) * BK);
    }
    // fragments: A row = wr + m*32 + (lane&31); k-chunk = ksub*2 + hi
    short8 af[MF][2], bfr[NF][2];
#pragma unroll
    for (int m = 0; m < MF; ++m) {
      int row = wr + m * 32 + r31;
      int sw = (row >> 1) & 3;
      af[m][0] = *(const short8*)&Al[cur][row * BK + ((hi       ^ sw) << 3)];
      af[m][1] = *(const short8*)&Al[cur][row * BK + (((2 + hi) ^ sw) << 3)];
    }
#pragma unroll
    for (int n = 0; n < NF; ++n) {
      int row = wc + n * 32 + r31;
      int sw = (row >> 1) & 3;
      bfr[n][0] = *(const short8*)&Bl[cur][row * BK + ((hi       ^ sw) << 3)];
      bfr[n][1] = *(const short8*)&Bl[cur][row * BK + (((2 + hi) ^ sw) << 3)];
    }
#pragma unroll
    for (int m = 0; m < MF; ++m)
#pragma unroll
      for (int n = 0; n < NF; ++n) {
        acc[m][n] = __builtin_amdgcn_mfma_f32_32x32x16_bf16(
            af[m][0], bfr[n][0], acc[m][n], 0, 0, 0);
        acc[m][n] = __builtin_amdgcn_mfma_f32_32x32x16_bf16(
            af[m][1], bfr[n][1], acc[m][n], 0, 0, 0);
      }
    ++cur; if (cur == 3) cur = 0;
  }

  // Epilogue.  C/D 32x32 layout (m74/m101):
  //   col = lane&31,  row = (r&3) + 8*(r>>2) + 4*(lane>>5),  r in [0,16)
  float mul = 1.0f, l2d = 0.0f;
  if (MODE == 1) {
    float dlv = scal[0];
    float decay = 1.0f / (1.0f + __expf(-dlv));   // sigmoid
    l2d = __log2f(decay);
  } else if (MODE == 2) {
    mul = scal[0];
  }

#pragma unroll
  for (int m = 0; m < MF; ++m) {
#pragma unroll
    for (int n = 0; n < NF; ++n) {
#pragma unroll
      for (int r = 0; r < 16; ++r) {
        int rloc = (r & 3) + 8 * (r >> 2) + 4 * hi;
        int row = bm + wr + m * 32 + rloc;
        int col = bn + wc + n * 32 + r31;
        float val = acc[m][n][r];
        if (MODE == 1) {
          int diff = col - row;
          float w = (diff > 0 && col < 2048)
                        ? exp2f((float)(diff - 1) * l2d) : 0.0f;
          int lc = bx * 128 + (wc + n * 32 + r31);   // band-local column
          ((bf16u*)Cout)[(long)z * sC + (long)row * ldC + lc] = f2bf(val * w);
        } else if (MODE == 2) {
          ((float*)Cout)[(long)z * sC + (long)row * ldC + col] = val * mul;
        } else {
          ((bf16u*)Cout)[(long)z * sC + (long)row * ldC + col] = f2bf(val);
        }
      }
    }
  }
}

// prep: one dispatch.  Blocks [0,8192): x f32->bf16 (float4/ushort4).
// Blocks [8192,10240): 32x32 transpose-convert tiles of the 4 weights.
__global__ __launch_bounds__(256)
void prep(const float4* __restrict__ x, ushort4* __restrict__ x16o,
          const float* __restrict__ Wq, const float* __restrict__ Wk,
          const float* __restrict__ Wv, const float* __restrict__ Wo,
          bf16u* __restrict__ WqT, bf16u* __restrict__ WkT,
          bf16u* __restrict__ WvT, bf16u* __restrict__ WoT)
{
  __shared__ float t[32][33];
  const int bid = blockIdx.x;
  const int tid = threadIdx.x;
  if (bid < 8192) {
    int i = bid * 256 + tid;
    float4 v = x[i];
    ushort4 o;
    o.x = f2bf(v.x); o.y = f2bf(v.y); o.z = f2bf(v.z); o.w = f2bf(v.w);
    x16o[i] = o;
    return;
  }
  const int wi = bid - 8192;
  const int w  = wi >> 9;          // weight id, 512 tiles each
  const int ti = wi & 511;
  const float* in; bf16u* out; int R, C;
  if (w == 0)      { in = Wq; out = WqT; R = 1024; C = 512; }
  else if (w == 1) { in = Wk; out = WkT; R = 1024; C = 512; }
  else if (w == 2) { in = Wv; out = WvT; R = 1024; C = 512; }
  else             { in = Wo; out = WoT; R = 512;  C = 1024; }
  const int nx = C >> 5;
  const int c0 = (ti % nx) * 32, r0 = (ti / nx) * 32;
  const int tx = tid & 31, ty = tid >> 5;   // 32 x 8
#pragma unroll
  for (int i = 0; i < 4; ++i)
    t[ty + 8 * i][tx] = in[(long)(r0 + ty + 8 * i) * C + c0 + tx];
  __syncthreads();
#pragma unroll
  for (int i = 0; i < 4; ++i)
    out[(long)(c0 + ty + 8 * i) * R + r0 + tx] = f2bf(t[tx][ty + 8 * i]);
}

// batched strided bf16 transpose: in [R x C, row-stride ldIn] -> out [C][R]
__global__ void tr16(const bf16u* __restrict__ in, bf16u* __restrict__ out,
                     int R, int C, int ldIn, long sIn, long sOut) {
  __shared__ bf16u t[32][33];
  in  += (long)blockIdx.z * sIn;
  out += (long)blockIdx.z * sOut;
  int c0 = blockIdx.x * 32, r0 = blockIdx.y * 32;
  int tx = threadIdx.x, ty = threadIdx.y;
#pragma unroll
  for (int i = 0; i < 4; ++i)
    t[ty + 8 * i][tx] = in[(long)(r0 + ty + 8 * i) * ldIn + c0 + tx];
  __syncthreads();
#pragma unroll
  for (int i = 0; i < 4; ++i)
    out[(long)(c0 + ty + 8 * i) * R + r0 + tx] = t[tx][ty + 8 * i];
}

extern "C" void kernel_launch(void* const* d_in, const int* in_sizes, int n_in,
                              void* d_out, int out_size, void* d_ws, size_t ws_size,
                              hipStream_t stream) {
  const float* x  = (const float*)d_in[0];
  const float* dl = (const float*)d_in[1];
  const float* sc = (const float*)d_in[2];
  const float* Wq = (const float*)d_in[3];
  const float* Wk = (const float*)d_in[4];
  const float* Wv = (const float*)d_in[5];
  const float* Wo = (const float*)d_in[6];

  const int B = 4, T = 2048, V = 1024, D = 512;
  const long MT = (long)B * T;   // 8192
  const int QKV = 3 * D;         // 1536
  const int BAND = 256;          // 2 x 128 band columns (delta 0..1)

  char* p = (char*)d_ws;
  auto alloc = [&](size_t bytes) { char* r = p; p += bytes; return r; };
  bf16u* x16 = (bf16u*)alloc((size_t)MT * V * 2);        // 16 MB
  bf16u* WqT = (bf16u*)alloc((size_t)D * V * 2);         // contiguous [1536][V]
  bf16u* WkT = (bf16u*)alloc((size_t)D * V * 2);
  bf16u* WvT = (bf16u*)alloc((size_t)D * V * 2);
  bf16u* WoT = (bf16u*)alloc((size_t)V * D * 2);
  bf16u* qkv = (bf16u*)alloc((size_t)MT * QKV * 2);      // 25 MB
  bf16u* vT  = (bf16u*)alloc((size_t)MT * D * 2 + 4096); // 8 MB + guard
  bf16u* Sb  = (bf16u*)alloc((size_t)B * T * BAND * 2);  // 4.2 MB band
  bf16u* R   = (bf16u*)alloc((size_t)MT * D * 2);        // 8 MB

  // 1. prep: x -> bf16 + all 4 weight transposes, one dispatch
  prep<<<dim3(8192 + 2048), 256, 0, stream>>>(
      (const float4*)x, (ushort4*)x16, Wq, Wk, Wv, Wo, WqT, WkT, WvT, WoT);

  // 2. qkv = x16 @ [Wq|Wk|Wv]^T  (M=8192, N=1536, K=1024), 128^2 -> 768 blocks
  gemm_bt<0, 128, 128><<<dim3(64 * 12, 1, 1), 256, 0, stream>>>(
      x16, WqT, qkv, V, V, V, QKV, 0, 0, 0, 12, nullptr);

  // 3. v transpose per batch: [T][D] (stride 1536) -> [D][T]
  tr16<<<dim3(D / 32, T / 32, B), dim3(32, 8), 0, stream>>>(
      qkv + 2 * D, vT, T, D, QKV, (long)T * QKV, (long)D * T);

  // 4. banded scores: S_band[b][t][delta*128+c], 128^2 tiles
  gemm_bt<1, 128, 128><<<dim3(16 * 2, 1, B), 256, 0, stream>>>(
      qkv, qkv + D, Sb, D, QKV, QKV, BAND,
      (long)T * QKV, (long)T * QKV, (long)T * BAND, 2, dl);

  // 5. banded retrieved: R rows [bm,+128) = S_band @ v[s = bm..bm+256)
  gemm_bt<3, 128, 128><<<dim3(16 * 4, 1, B), 256, 0, stream>>>(
      Sb, vT, R, BAND, BAND, T, D,
      (long)T * BAND, (long)1 << 20, (long)T * D, 4, nullptr);

  // 6. out = R @ Wo^T * scale  (M=8192, N=1024, K=512), 128^2 -> 512 blocks
  gemm_bt<2, 128, 128><<<dim3(64 * 8, 1, 1), 256, 0, stream>>>(
      R, WoT, d_out, D, D, D, V, 0, 0, 0, 8, sc);
}